// Round 1
// baseline (104.047 us; speedup 1.0000x reference)
//
#include <hip/hip_runtime.h>

// Problem constants: out[c,b,g] = sum_s prod_l x[b, I[c,g,s,l]]
#define Cc 16
#define Gg 8192
#define Ss 8
#define Ll 3
#define Bb 32

// --- Kernel 1: transpose x (B,G) -> xT (G,B) so a gathered row is 128 B contiguous.
__global__ __launch_bounds__(256) void transpose_x(const float* __restrict__ x,
                                                   float* __restrict__ xT) {
    int t = blockIdx.x * 256 + threadIdx.x;   // 0 .. B*G-1, coalesced read
    int b = t >> 13;                          // t / G
    int g = t & (Gg - 1);                     // t % G
    xT[g * Bb + b] = x[t];
}

// --- Kernel 2: main clause evaluation.
// Lane layout: b = tid&31 (inner), j = tid>>5 selects one of 8 g's per block.
// Gather xT[idx*32 + b]: 32 lanes with same idx read one contiguous 128 B row.
// Index loads: same address across the 32 b-lanes -> broadcast, ~free.
__global__ __launch_bounds__(256) void clause_kernel(const float* __restrict__ xT,
                                                     const int* __restrict__ I,
                                                     float* __restrict__ out) {
    const int tid = threadIdx.x;
    const int b = tid & 31;
    const int j = tid >> 5;                 // 0..7
    const int g = blockIdx.x * 8 + j;
    const int c = blockIdx.y;

    // 24 indices for this (c,g), 16B-aligned (offset is a multiple of 96 B).
    const int* Icg = I + (size_t)(c * Gg + g) * (Ss * Ll);
    const int4* I4 = (const int4*)Icg;

    int idx[Ss * Ll];
    #pragma unroll
    for (int k = 0; k < 6; ++k) {
        int4 v = I4[k];
        idx[4 * k + 0] = v.x;
        idx[4 * k + 1] = v.y;
        idx[4 * k + 2] = v.z;
        idx[4 * k + 3] = v.w;
    }

    float sum = 0.f;
    #pragma unroll
    for (int s = 0; s < Ss; ++s) {
        float p0 = xT[idx[3 * s + 0] * Bb + b];
        float p1 = xT[idx[3 * s + 1] * Bb + b];
        float p2 = xT[idx[3 * s + 2] * Bb + b];
        sum += p0 * p1 * p2;
    }

    // out is (C, B, G): contiguous in g. Lanes here differ in b (stride G) ->
    // uncoalesced 4B stores, but L2 write-combines; HBM write stays ~16 MB.
    out[(size_t)(c * Bb + b) * Gg + g] = sum;
}

// --- Fallback (no workspace): gather directly from x (B,G); uncoalesced but correct.
__global__ __launch_bounds__(256) void clause_kernel_direct(const float* __restrict__ x,
                                                            const int* __restrict__ I,
                                                            float* __restrict__ out) {
    const int tid = threadIdx.x;
    const int b = tid & 31;
    const int j = tid >> 5;
    const int g = blockIdx.x * 8 + j;
    const int c = blockIdx.y;

    const int* Icg = I + (size_t)(c * Gg + g) * (Ss * Ll);
    float sum = 0.f;
    #pragma unroll
    for (int s = 0; s < Ss; ++s) {
        float p0 = x[(size_t)b * Gg + Icg[3 * s + 0]];
        float p1 = x[(size_t)b * Gg + Icg[3 * s + 1]];
        float p2 = x[(size_t)b * Gg + Icg[3 * s + 2]];
        sum += p0 * p1 * p2;
    }
    out[(size_t)(c * Bb + b) * Gg + g] = sum;
}

extern "C" void kernel_launch(void* const* d_in, const int* in_sizes, int n_in,
                              void* d_out, int out_size, void* d_ws, size_t ws_size,
                              hipStream_t stream) {
    const float* x = (const float*)d_in[0];
    const int* I = (const int*)d_in[1];
    float* out = (float*)d_out;

    const size_t xT_bytes = (size_t)Bb * Gg * sizeof(float);  // 1 MB

    if (ws_size >= xT_bytes) {
        float* xT = (float*)d_ws;
        transpose_x<<<(Bb * Gg) / 256, 256, 0, stream>>>(x, xT);
        clause_kernel<<<dim3(Gg / 8, Cc), 256, 0, stream>>>(xT, I, out);
    } else {
        clause_kernel_direct<<<dim3(Gg / 8, Cc), 256, 0, stream>>>(x, I, out);
    }
}

// Round 2
// 92.626 us; speedup vs baseline: 1.1233x; 1.1233x over previous
//
#include <hip/hip_runtime.h>

// out[c,b,g] = sum_{s<8} prod_{l<3} x[b, I[c,g,s,l]]
#define Cc 16
#define Gg 8192
#define Ss 8
#define Ll 3
#define Bb 32

#define TILE_G 64
#define ROUNDS (TILE_G / 8)   // 8 rounds of 8 g's each (256 thr = 32 b x 8 g)

// --- Kernel 1: tiled transpose x (B,G) -> xT (G,B). Both sides coalesced via LDS.
__global__ __launch_bounds__(256) void transpose_x(const float* __restrict__ x,
                                                   float* __restrict__ xT) {
    __shared__ float t[32][33];           // [b][g_local], +1 pad
    const int g0 = blockIdx.x * 32;
    const int tx = threadIdx.x & 31;
    const int ty = threadIdx.x >> 5;      // 0..7
    #pragma unroll
    for (int r = 0; r < 4; ++r) {
        int b = r * 8 + ty;
        t[b][tx] = x[(size_t)b * Gg + g0 + tx];   // coalesced 128 B per half-wave
    }
    __syncthreads();
    #pragma unroll
    for (int r = 0; r < 4; ++r) {
        int gl = r * 8 + ty;
        xT[(size_t)(g0 + gl) * Bb + tx] = t[tx][gl];  // coalesced 128 B per half-wave
    }
}

// --- Kernel 2: clause evaluation.
// Lane layout for gathers: b = tid&31 (inner) -> 32 lanes read one contiguous
// 128 B row xT[idx*32 .. +31]; 2 rows per wave instr = 4x64B sectors (min TA cost).
// 8 rounds per thread with index prefetch (gathers issued BEFORE next idx loads,
// so consuming gathers doesn't drain the prefetch in the FIFO vmcnt queue).
// Output staged in LDS tile, stored coalesced (4x256 B runs per wave).
__global__ __launch_bounds__(256) void clause_kernel(const float* __restrict__ xT,
                                                     const int* __restrict__ I,
                                                     float* __restrict__ out) {
    const int tid = threadIdx.x;
    const int b = tid & 31;
    const int j = tid >> 5;                 // 0..7
    const int c = blockIdx.y;
    const int g0 = blockIdx.x * TILE_G;

    __shared__ float tile[Bb][TILE_G + 1];  // [b][g_local], +1 pad

    // Indices for (c, g0 + r*8 + j): 24 ints, 96 B offset -> 16 B aligned.
    const int4* I4 = (const int4*)(I + ((size_t)c * Gg + g0 + j) * (Ss * Ll));
    // round stride: 8 g's * 24 ints = 192 ints = 48 int4

    int4 nxt[6];
    #pragma unroll
    for (int k = 0; k < 6; ++k) nxt[k] = I4[k];

    #pragma unroll
    for (int r = 0; r < ROUNDS; ++r) {
        int idx[Ss * Ll];
        #pragma unroll
        for (int k = 0; k < 6; ++k) {
            idx[4 * k + 0] = nxt[k].x;
            idx[4 * k + 1] = nxt[k].y;
            idx[4 * k + 2] = nxt[k].z;
            idx[4 * k + 3] = nxt[k].w;
        }
        // Issue all 24 independent gathers first (max MLP).
        float v[Ss * Ll];
        #pragma unroll
        for (int k = 0; k < Ss * Ll; ++k)
            v[k] = xT[(idx[k] << 5) | b];
        // Prefetch next round's indices AFTER the gathers: FIFO vmcnt means the
        // product computation only waits on gathers, prefetch stays in flight.
        if (r + 1 < ROUNDS) {
            const int4* p = I4 + (r + 1) * 48;
            #pragma unroll
            for (int k = 0; k < 6; ++k) nxt[k] = p[k];
        }
        float sum = 0.f;
        #pragma unroll
        for (int s = 0; s < Ss; ++s)
            sum += v[3 * s + 0] * v[3 * s + 1] * v[3 * s + 2];
        tile[b][r * 8 + j] = sum;           // banks (b + g)%32: conflict-free
    }
    __syncthreads();

    // Coalesced store: out is (C,B,G), g inner. 2048 floats = 512 float4.
    // fid = i*256 + tid: row b' = fid>>4 (16 quads/row), quad q = fid&15.
    // A wave covers 4 full 256 B contiguous rows.
    #pragma unroll
    for (int i = 0; i < 2; ++i) {
        int fid = i * 256 + tid;
        int bp = fid >> 4;
        int q = fid & 15;
        float4 val;
        val.x = tile[bp][4 * q + 0];
        val.y = tile[bp][4 * q + 1];
        val.z = tile[bp][4 * q + 2];
        val.w = tile[bp][4 * q + 3];
        float4* dst = (float4*)(out + ((size_t)(c * Bb + bp)) * Gg + g0);
        dst[q] = val;
    }
}

// --- Fallback (no workspace): gather directly from x (B,G); uncoalesced but correct.
__global__ __launch_bounds__(256) void clause_kernel_direct(const float* __restrict__ x,
                                                            const int* __restrict__ I,
                                                            float* __restrict__ out) {
    const int tid = threadIdx.x;
    const int b = tid & 31;
    const int j = tid >> 5;
    const int g = blockIdx.x * 8 + j;
    const int c = blockIdx.y;

    const int* Icg = I + (size_t)(c * Gg + g) * (Ss * Ll);
    float sum = 0.f;
    #pragma unroll
    for (int s = 0; s < Ss; ++s) {
        float p0 = x[(size_t)b * Gg + Icg[3 * s + 0]];
        float p1 = x[(size_t)b * Gg + Icg[3 * s + 1]];
        float p2 = x[(size_t)b * Gg + Icg[3 * s + 2]];
        sum += p0 * p1 * p2;
    }
    out[(size_t)(c * Bb + b) * Gg + g] = sum;
}

extern "C" void kernel_launch(void* const* d_in, const int* in_sizes, int n_in,
                              void* d_out, int out_size, void* d_ws, size_t ws_size,
                              hipStream_t stream) {
    const float* x = (const float*)d_in[0];
    const int* I = (const int*)d_in[1];
    float* out = (float*)d_out;

    const size_t xT_bytes = (size_t)Bb * Gg * sizeof(float);  // 1 MB

    if (ws_size >= xT_bytes) {
        float* xT = (float*)d_ws;
        transpose_x<<<Gg / 32, 256, 0, stream>>>(x, xT);
        clause_kernel<<<dim3(Gg / TILE_G, Cc), 256, 0, stream>>>(xT, I, out);
    } else {
        clause_kernel_direct<<<dim3(Gg / 8, Cc), 256, 0, stream>>>(x, I, out);
    }
}

// Round 3
// 84.272 us; speedup vs baseline: 1.2347x; 1.0991x over previous
//
#include <hip/hip_runtime.h>

// out[c,b,g] = sum_{s<8} prod_{l<3} x[b, I[c,g,s,l]]
#define Cc 16
#define Gg 8192
#define Ss 8
#define Ll 3
#define Bb 32

// --- Kernel 1: tiled transpose x (B,G) -> xT (G,B). Both sides coalesced via LDS.
__global__ __launch_bounds__(256) void transpose_x(const float* __restrict__ x,
                                                   float* __restrict__ xT) {
    __shared__ float t[32][33];           // [b][g_local], +1 pad
    const int g0 = blockIdx.x * 32;
    const int tx = threadIdx.x & 31;
    const int ty = threadIdx.x >> 5;      // 0..7
    #pragma unroll
    for (int r = 0; r < 4; ++r) {
        int b = r * 8 + ty;
        t[b][tx] = x[(size_t)b * Gg + g0 + tx];
    }
    __syncthreads();
    #pragma unroll
    for (int r = 0; r < 4; ++r) {
        int gl = r * 8 + ty;
        xT[(size_t)(g0 + gl) * Bb + tx] = t[tx][gl];
    }
}

// --- Kernel 2: clause evaluation, float4 (b-quad) gathers.
// TA (addr-gen) is the bottleneck at ~4 addr/cyc/CU: minimize per-lane
// addresses. Lane = (g_sub = tid>>3, bq = tid&7); each gather instruction
// fetches 8 random 128 B lines fully (8 lanes x float4 per line) = 1 KB
// useful per instr, 4x fewer VMEM instrs than the 4 B/lane version.
__global__ __launch_bounds__(256) void clause_kernel(const float* __restrict__ xT,
                                                     const int* __restrict__ I,
                                                     float* __restrict__ out) {
    const int tid = threadIdx.x;
    const int bq = tid & 7;                 // b-quad: covers b = 4*bq .. 4*bq+3
    const int gl = tid >> 3;                // 0..31 local g
    const int c = blockIdx.y;
    const int g0 = blockIdx.x * 32;
    const int g = g0 + gl;

    __shared__ float tile[Bb][33];          // [b][g_local], +1 pad

    // 24 indices for (c,g); byte offset multiple of 96 -> 16 B aligned.
    const int4* I4 = (const int4*)(I + ((size_t)c * Gg + g) * (Ss * Ll));
    int4 q0 = I4[0], q1 = I4[1], q2 = I4[2], q3 = I4[3], q4 = I4[4], q5 = I4[5];
    int idx[Ss * Ll] = {q0.x, q0.y, q0.z, q0.w, q1.x, q1.y, q1.z, q1.w,
                        q2.x, q2.y, q2.z, q2.w, q3.x, q3.y, q3.z, q3.w,
                        q4.x, q4.y, q4.z, q4.w, q5.x, q5.y, q5.z, q5.w};

    const float4* xT4 = (const float4*)xT;  // row g = 8 float4s
    float4 v[Ss * Ll];
    #pragma unroll
    for (int k = 0; k < Ss * Ll; ++k)
        v[k] = xT4[(idx[k] << 3) | bq];     // 32-bit elem index, 16 B aligned

    float4 sum = {0.f, 0.f, 0.f, 0.f};
    #pragma unroll
    for (int s = 0; s < Ss; ++s) {
        sum.x += v[3 * s].x * v[3 * s + 1].x * v[3 * s + 2].x;
        sum.y += v[3 * s].y * v[3 * s + 1].y * v[3 * s + 2].y;
        sum.z += v[3 * s].z * v[3 * s + 1].z * v[3 * s + 2].z;
        sum.w += v[3 * s].w * v[3 * s + 1].w * v[3 * s + 2].w;
    }

    tile[4 * bq + 0][gl] = sum.x;           // banks (4bq+gl+i)%32: <=2-way, free
    tile[4 * bq + 1][gl] = sum.y;
    tile[4 * bq + 2][gl] = sum.z;
    tile[4 * bq + 3][gl] = sum.w;
    __syncthreads();

    // Coalesced store: out (C,B,G), g inner. Block tile = 32 b x 32 g = 4 KB.
    // Wave covers 8 rows of 128 B contiguous each.
    const int bp = tid >> 3;                // 0..31
    const int qq = tid & 7;                 // 0..7 float4s per row
    float4 o;
    o.x = tile[bp][4 * qq + 0];
    o.y = tile[bp][4 * qq + 1];
    o.z = tile[bp][4 * qq + 2];
    o.w = tile[bp][4 * qq + 3];
    *(float4*)(out + ((size_t)(c * Bb + bp)) * Gg + g0 + 4 * qq) = o;
}

// --- Fallback (no workspace): gather directly from x (B,G); uncoalesced but correct.
__global__ __launch_bounds__(256) void clause_kernel_direct(const float* __restrict__ x,
                                                            const int* __restrict__ I,
                                                            float* __restrict__ out) {
    const int tid = threadIdx.x;
    const int b = tid & 31;
    const int j = tid >> 5;
    const int g = blockIdx.x * 8 + j;
    const int c = blockIdx.y;

    const int* Icg = I + (size_t)(c * Gg + g) * (Ss * Ll);
    float sum = 0.f;
    #pragma unroll
    for (int s = 0; s < Ss; ++s) {
        float p0 = x[(size_t)b * Gg + Icg[3 * s + 0]];
        float p1 = x[(size_t)b * Gg + Icg[3 * s + 1]];
        float p2 = x[(size_t)b * Gg + Icg[3 * s + 2]];
        sum += p0 * p1 * p2;
    }
    out[(size_t)(c * Bb + b) * Gg + g] = sum;
}

extern "C" void kernel_launch(void* const* d_in, const int* in_sizes, int n_in,
                              void* d_out, int out_size, void* d_ws, size_t ws_size,
                              hipStream_t stream) {
    const float* x = (const float*)d_in[0];
    const int* I = (const int*)d_in[1];
    float* out = (float*)d_out;

    const size_t xT_bytes = (size_t)Bb * Gg * sizeof(float);  // 1 MB

    if (ws_size >= xT_bytes) {
        float* xT = (float*)d_ws;
        transpose_x<<<Gg / 32, 256, 0, stream>>>(x, xT);
        clause_kernel<<<dim3(Gg / 32, Cc), 256, 0, stream>>>(xT, I, out);
    } else {
        clause_kernel_direct<<<dim3(Gg / 8, Cc), 256, 0, stream>>>(x, I, out);
    }
}

// Round 4
// 83.805 us; speedup vs baseline: 1.2415x; 1.0056x over previous
//
#include <hip/hip_runtime.h>

// out[c,b,g] = sum_{s<8} prod_{l<3} x[b, I[c,g,s,l]]
#define Cc 16
#define Gg 8192
#define Ss 8
#define Ll 3
#define Bb 32

#define SLICES 16          // b-pairs: slice z holds b = 2z, 2z+1
#define GTILE 64           // g's per block
#define THREADS 512

// --- Kernel 1: build pairs-major layout xs[z][g] = {x[2z][g], x[2z+1][g]}.
// All loads/stores fully coalesced (g contiguous across lanes). 1 MB total.
__global__ __launch_bounds__(256) void build_xpairs(const float* __restrict__ x,
                                                    float2* __restrict__ xs) {
    int t = blockIdx.x * 256 + threadIdx.x;   // 0 .. SLICES*G-1
    int z = t >> 13;                          // t / G
    int g = t & (Gg - 1);                     // t % G
    float a = x[(size_t)(2 * z) * Gg + g];
    float b = x[(size_t)(2 * z + 1) * Gg + g];
    xs[t] = make_float2(a, b);                // t == z*G + g
}

// --- Kernel 2: clause evaluation with LDS-resident gather.
// The global-gather TCP path is capped at ~16 B/cyc/CU (per-lane-address
// bound, measured R1/R3); LDS random gather runs ~60 B/cyc/CU. Stage 2 full
// b-rows (all 8192 g, float2 = 64 KB) in LDS, gather with ds_read_b64.
// 2 blocks/CU resident (64 KB LDS, <=128 VGPR) overlap staging with gathers.
__global__ __launch_bounds__(THREADS, 4) void clause_kernel(const float2* __restrict__ xs,
                                                            const int* __restrict__ I,
                                                            float* __restrict__ out) {
    __shared__ float2 xl[Gg];                 // 64 KB
    const int tid = threadIdx.x;
    const int z = blockIdx.y;                 // b-pair slice
    const int g0 = blockIdx.x * GTILE;

    // Stage slice: 64 KB contiguous, float4 loads + b128 LDS writes
    // (lane-contiguous -> uniform banks, 8-cyc floor).
    const float4* src = (const float4*)(xs + (size_t)z * Gg);
    float4* dst = (float4*)xl;
    #pragma unroll
    for (int i = 0; i < 8; ++i)
        dst[tid + i * THREADS] = src[tid + i * THREADS];
    __syncthreads();

    #pragma unroll
    for (int it = 0; it < 2; ++it) {
        int w = it * THREADS + tid;           // 0..1023
        int c = w >> 6;                       // wave-uniform: 64 consecutive w share c
        int gl = w & 63;
        int g = g0 + gl;

        // 24 indices, 16 B aligned (96 B offset). Global loads (vmcnt) don't
        // block on the ds gather queue (lgkmcnt) -> iter 1's idx prefetch
        // overlaps iter 0's gathers.
        const int4* I4 = (const int4*)(I + ((size_t)c * Gg + g) * (Ss * Ll));
        int4 q0 = I4[0], q1 = I4[1], q2 = I4[2], q3 = I4[3], q4 = I4[4], q5 = I4[5];
        int idx[Ss * Ll] = {q0.x, q0.y, q0.z, q0.w, q1.x, q1.y, q1.z, q1.w,
                            q2.x, q2.y, q2.z, q2.w, q3.x, q3.y, q3.z, q3.w,
                            q4.x, q4.y, q4.z, q4.w, q5.x, q5.y, q5.z, q5.w};

        float2 v[Ss * Ll];
        #pragma unroll
        for (int k = 0; k < Ss * Ll; ++k)
            v[k] = xl[idx[k]];                // ds_read_b64, random bank-pair

        float2 s = {0.f, 0.f};
        #pragma unroll
        for (int q = 0; q < Ss; ++q) {
            s.x += v[3 * q].x * v[3 * q + 1].x * v[3 * q + 2].x;
            s.y += v[3 * q].y * v[3 * q + 1].y * v[3 * q + 2].y;
        }

        // out (C,B,G): b = 2z, 2z+1. g contiguous across lanes -> coalesced.
        float* op = out + ((size_t)(c * Bb + 2 * z)) * Gg + g;
        op[0] = s.x;
        op[Gg] = s.y;
    }
}

// --- Fallback (no workspace): gather directly from x (B,G); slow but correct.
__global__ __launch_bounds__(256) void clause_kernel_direct(const float* __restrict__ x,
                                                            const int* __restrict__ I,
                                                            float* __restrict__ out) {
    const int tid = threadIdx.x;
    const int b = tid & 31;
    const int j = tid >> 5;
    const int g = blockIdx.x * 8 + j;
    const int c = blockIdx.y;

    const int* Icg = I + (size_t)(c * Gg + g) * (Ss * Ll);
    float sum = 0.f;
    #pragma unroll
    for (int s = 0; s < Ss; ++s) {
        float p0 = x[(size_t)b * Gg + Icg[3 * s + 0]];
        float p1 = x[(size_t)b * Gg + Icg[3 * s + 1]];
        float p2 = x[(size_t)b * Gg + Icg[3 * s + 2]];
        sum += p0 * p1 * p2;
    }
    out[(size_t)(c * Bb + b) * Gg + g] = sum;
}

extern "C" void kernel_launch(void* const* d_in, const int* in_sizes, int n_in,
                              void* d_out, int out_size, void* d_ws, size_t ws_size,
                              hipStream_t stream) {
    const float* x = (const float*)d_in[0];
    const int* I = (const int*)d_in[1];
    float* out = (float*)d_out;

    const size_t xs_bytes = (size_t)SLICES * Gg * sizeof(float2);  // 1 MB

    if (ws_size >= xs_bytes) {
        float2* xs = (float2*)d_ws;
        build_xpairs<<<(SLICES * Gg) / 256, 256, 0, stream>>>(x, xs);
        clause_kernel<<<dim3(Gg / GTILE, SLICES), THREADS, 0, stream>>>(xs, I, out);
    } else {
        clause_kernel_direct<<<dim3(Gg / 8, Cc), 256, 0, stream>>>(x, I, out);
    }
}